// Round 3
// baseline (311.665 us; speedup 1.0000x reference)
//
#include <hip/hip_runtime.h>
#include <stdint.h>
#include <stddef.h>

// ---------------------------------------------------------------------------
// SelfAttention: out = softmax((x W1^T + b1)(x W2^T + b2)^T) (x W2^T + b2)
// B=4, L=2048, D=1024. fp32 in/out; fp16 MFMA internals (tolerance is
// bf16-grade, fp16 has 8x the mantissa).
// Round 3 changes vs round 2:
//  - XOR k-chunk swizzle on all LDS tiles (kills ds_read phase conflicts;
//    implemented by permuting DMA *source* addresses, LDS lands linearly)
//  - score kernel: 256x128 tile (AI 64->85 FLOP/B, LDS bytes/MFMA 500->375)
//  - proj1+proj2 fused into one kernel (x staged once, both W tiles)
//  - Vt written via padded-LDS transpose + coalesced f16x8 stores
//    (was: 64 scalar 2B stores/lane at 4KB stride = ~16x write amplification)
// ---------------------------------------------------------------------------

typedef _Float16  f16_t;
typedef _Float16  f16x8 __attribute__((ext_vector_type(8)));
typedef _Float16  f16x4 __attribute__((ext_vector_type(4)));
typedef float     f32x4 __attribute__((ext_vector_type(4)));

__device__ __forceinline__ f32x4 mfma16(f16x8 a, f16x8 b, f32x4 c) {
  return __builtin_amdgcn_mfma_f32_16x16x32_f16(a, b, c, 0, 0, 0);
}

__device__ __forceinline__ void async_copy16(const f16_t* g, f16_t* l) {
  // global -> LDS direct DMA, 16B/lane; LDS dest = wave-uniform base+lane*16.
  __builtin_amdgcn_global_load_lds(
      (const __attribute__((address_space(1))) unsigned int*)(g),
      (__attribute__((address_space(3))) unsigned int*)(l),
      16, 0, 0);
}

// C = A * B^T on a (RT*32) x 128 tile. K = nk*32, K contiguous in both.
// 4 waves in 2x2; wave quadrant (RT*16) x 64. LDS tile layout [row][32],
// with the 4 16B k-chunks of each row XOR-swizzled by (row>>1)&3.
template <int RT>
__device__ __forceinline__ void gemm_core(
    const f16_t* __restrict__ A, const f16_t* __restrict__ B,
    int lda, int ldb, int nk,
    f16_t* __restrict__ As, f16_t* __restrict__ Bs, f32x4 (&acc)[RT][4])
{
  const int tid  = threadIdx.x;
  const int lane = tid & 63;
  const int w    = tid >> 6;
  const int wr   = (w >> 1) * (RT * 16);
  const int wc   = (w & 1) * 64;
  const int quad = lane >> 4;
  const int l16  = lane & 15;
  // read-side swizzle: chunk position of global chunk `quad` in row (..+l16)
  const int sw   = (quad ^ ((l16 >> 1) & 3)) * 8;

  // staging: thread tid owns LDS chunk slot tid(+256h) = (row, pos tid&3);
  // fetch global chunk (tid&3)^((row>>1)&3) so LDS holds the swizzled layout.
  const int r0  = tid >> 2;
  const int kc0 = ((tid & 3) ^ ((r0 >> 1) & 3)) * 8;

  const f16_t* Ag = A + (size_t)r0 * lda + kc0;
  const f16_t* Bg = B + (size_t)r0 * ldb + kc0;

  for (int kt = 0; kt < nk; ++kt) {
#pragma unroll
    for (int h = 0; h < RT / 2; ++h)
      async_copy16(Ag + (size_t)(64 * h) * lda, As + (tid + 256 * h) * 8);
    async_copy16(Bg, Bs + tid * 8);
    async_copy16(Bg + (size_t)64 * ldb, Bs + (tid + 256) * 8);
    __syncthreads();   // vmcnt(0) drain + barrier

    f16x8 af[RT], bf[4];
#pragma unroll
    for (int i = 0; i < RT; ++i)
      af[i] = *(const f16x8*)(As + (wr + i * 16 + l16) * 32 + sw);
#pragma unroll
    for (int j = 0; j < 4; ++j)
      bf[j] = *(const f16x8*)(Bs + (wc + j * 16 + l16) * 32 + sw);
#pragma unroll
    for (int i = 0; i < RT; ++i)
#pragma unroll
      for (int j = 0; j < 4; ++j)
        acc[i][j] = mfma16(af[i], bf[j], acc[i][j]);

    __syncthreads();
    Ag += 32; Bg += 32;
  }
}

// ---------------------------------------------------------------------------
// 0) fp32 -> fp16 converter, 8 elems/thread.
__global__ __launch_bounds__(256) void cvt_kernel(
    const float* __restrict__ in, f16_t* __restrict__ out)
{
  const size_t i = ((size_t)blockIdx.x * 256 + threadIdx.x) * 8;
  f32x4 a = *(const f32x4*)(in + i);
  f32x4 b = *(const f32x4*)(in + i + 4);
  f16x8 o;
#pragma unroll
  for (int k = 0; k < 4; ++k) { o[k] = (f16_t)a[k]; o[k + 4] = (f16_t)b[k]; }
  *(f16x8*)(out + i) = o;
}

// ---------------------------------------------------------------------------
// 1) fused projection: Q = xW1^T+b1, V = xW2^T+b2 (both fp16), plus
//    Vt[b][col][key] via LDS transpose. x tile staged once for both GEMMs.
__global__ __launch_bounds__(256) void proj_qv_kernel(
    const f16_t* __restrict__ X, const f16_t* __restrict__ W1,
    const f16_t* __restrict__ W2, const float* __restrict__ b1,
    const float* __restrict__ b2, f16_t* __restrict__ Q,
    f16_t* __restrict__ V, f16_t* __restrict__ Vt)
{
  __shared__ __align__(16) f16_t Xs[128 * 32];
  __shared__ __align__(16) f16_t W1s[128 * 32];
  __shared__ __align__(16) f16_t W2s[128 * 32];
  __shared__ __align__(16) f16_t Ts[128 * 136];   // V^T, padded pitch 136

  const int m0 = blockIdx.x * 128;
  const int n0 = blockIdx.y * 128;

  const int tid  = threadIdx.x;
  const int lane = tid & 63;
  const int w    = tid >> 6;
  const int wr   = (w >> 1) * 64;
  const int wc   = (w & 1) * 64;
  const int quad = lane >> 4;
  const int l16  = lane & 15;
  const int sw   = (quad ^ ((l16 >> 1) & 3)) * 8;
  const int r0   = tid >> 2;
  const int kc0  = ((tid & 3) ^ ((r0 >> 1) & 3)) * 8;

  const f16_t* Xg = X + (size_t)(m0 + r0) * 1024 + kc0;
  const f16_t* G1 = W1 + (size_t)(n0 + r0) * 1024 + kc0;
  const f16_t* G2 = W2 + (size_t)(n0 + r0) * 1024 + kc0;

  f32x4 accQ[4][4] = {};
  f32x4 accV[4][4] = {};

  for (int kt = 0; kt < 32; ++kt) {
    async_copy16(Xg,                      Xs + tid * 8);
    async_copy16(Xg + (size_t)64 * 1024,  Xs + (tid + 256) * 8);
    async_copy16(G1,                      W1s + tid * 8);
    async_copy16(G1 + (size_t)64 * 1024,  W1s + (tid + 256) * 8);
    async_copy16(G2,                      W2s + tid * 8);
    async_copy16(G2 + (size_t)64 * 1024,  W2s + (tid + 256) * 8);
    __syncthreads();

    f16x8 xf[4], w1f[4], w2f[4];
#pragma unroll
    for (int i = 0; i < 4; ++i) {
      xf[i]  = *(const f16x8*)(Xs  + (wr + i * 16 + l16) * 32 + sw);
      w1f[i] = *(const f16x8*)(W1s + (wc + i * 16 + l16) * 32 + sw);
      w2f[i] = *(const f16x8*)(W2s + (wc + i * 16 + l16) * 32 + sw);
    }
#pragma unroll
    for (int i = 0; i < 4; ++i)
#pragma unroll
      for (int j = 0; j < 4; ++j) {
        accQ[i][j] = mfma16(xf[i], w1f[j], accQ[i][j]);
        accV[i][j] = mfma16(xf[i], w2f[j], accV[i][j]);
      }
    __syncthreads();
    Xg += 32; G1 += 32; G2 += 32;
  }

  // epilogue: natural Q/V stores + V^T into padded LDS (b64 per 4 rows)
#pragma unroll
  for (int j = 0; j < 4; ++j) {
    const int cl  = wc + j * 16 + l16;       // local col
    const int col = n0 + cl;
    const float bq = b1[col], bv = b2[col];
#pragma unroll
    for (int i = 0; i < 4; ++i) {
      const int rowb = wr + i * 16 + quad * 4;   // local row base
      f16x4 tv;
#pragma unroll
      for (int r = 0; r < 4; ++r) {
        const int row = m0 + rowb + r;
        const float q = accQ[i][j][r] + bq;
        const float v = accV[i][j][r] + bv;
        Q[(size_t)row * 1024 + col] = (f16_t)q;
        V[(size_t)row * 1024 + col] = (f16_t)v;
        tv[r] = (f16_t)v;
      }
      *(f16x4*)(&Ts[cl * 136 + rowb]) = tv;
    }
  }
  __syncthreads();

  // coalesced Vt stores: Vt[b][n0+c][m0&2047 .. +127]
  const size_t vtbase = ((size_t)(m0 >> 11) << 21) + (size_t)n0 * 2048 + (m0 & 2047);
#pragma unroll
  for (int rep = 0; rep < 8; ++rep) {
    const int idx = rep * 256 + tid;
    const int c = idx >> 4, ch = idx & 15;
    f16x8 vv = *(const f16x8*)(&Ts[c * 136 + ch * 8]);
    *(f16x8*)(&Vt[vtbase + (size_t)c * 2048 + ch * 8]) = vv;
  }
}

// ---------------------------------------------------------------------------
// 2) scores: S[b][q][k] = Q[b,q,:] . V[b,k,:]  (fp32). 256x128 tile.
__global__ __launch_bounds__(256) void score_kernel(
    const f16_t* __restrict__ Q, const f16_t* __restrict__ V,
    float* __restrict__ S)
{
  __shared__ __align__(16) f16_t As[256 * 32];   // 16 KB
  __shared__ __align__(16) f16_t Bs[128 * 32];   //  8 KB
  const int m0 = blockIdx.x * 256;
  const int n0 = blockIdx.y * 128;
  const size_t boff = (size_t)blockIdx.z * 2048 * 1024;

  f32x4 acc[8][4] = {};
  gemm_core<8>(Q + boff + (size_t)m0 * 1024, V + boff + (size_t)n0 * 1024,
               1024, 1024, 1024 / 32, As, Bs, acc);

  float* Sb = S + (size_t)blockIdx.z * 2048 * 2048;
  const int lane = threadIdx.x & 63;
  const int w    = threadIdx.x >> 6;
  const int wr   = (w >> 1) * 128, wc = (w & 1) * 64;
  const int quad = lane >> 4,      l16 = lane & 15;

#pragma unroll
  for (int i = 0; i < 8; ++i)
#pragma unroll
    for (int j = 0; j < 4; ++j)
#pragma unroll
      for (int r = 0; r < 4; ++r) {
        const int row = m0 + wr + i * 16 + quad * 4 + r;
        const int col = n0 + wc + j * 16 + l16;
        Sb[(size_t)row * 2048 + col] = acc[i][j][r];
      }
}

// ---------------------------------------------------------------------------
// 3) softmax over each 2048-fp32 row of S; fp16 P written in-place.
__global__ __launch_bounds__(256) void softmax_kernel(float* __restrict__ S)
{
  float* src = S + (size_t)blockIdx.x * 2048;
  f16_t* dst = (f16_t*)src;
  const int tid  = threadIdx.x;
  const int lane = tid & 63;
  const int w    = tid >> 6;

  f32x4 va = *((const f32x4*)src + tid * 2);
  f32x4 vb = *((const f32x4*)src + tid * 2 + 1);
  float f[8];
#pragma unroll
  for (int k = 0; k < 4; ++k) { f[k] = va[k]; f[k + 4] = vb[k]; }

  float m = f[0];
#pragma unroll
  for (int k = 1; k < 8; ++k) m = fmaxf(m, f[k]);
#pragma unroll
  for (int off = 32; off >= 1; off >>= 1) m = fmaxf(m, __shfl_xor(m, off));

  __shared__ float red[4];
  if (lane == 0) red[w] = m;
  __syncthreads();
  m = fmaxf(fmaxf(red[0], red[1]), fmaxf(red[2], red[3]));

  float s = 0.f;
#pragma unroll
  for (int k = 0; k < 8; ++k) { f[k] = __expf(f[k] - m); s += f[k]; }
#pragma unroll
  for (int off = 32; off >= 1; off >>= 1) s += __shfl_xor(s, off);
  __syncthreads();
  if (lane == 0) red[w] = s;
  __syncthreads();
  s = (red[0] + red[1]) + (red[2] + red[3]);
  const float inv = 1.f / s;

  f16x8 o;
#pragma unroll
  for (int k = 0; k < 8; ++k) o[k] = (f16_t)(f[k] * inv);
  *((f16x8*)dst + tid) = o;
}

// ---------------------------------------------------------------------------
// 4) out[b][q][d] = sum_k P[b][q][k] * Vt[b][d][k] -> fp32. P pitch 4096 f16.
__global__ __launch_bounds__(256) void out_kernel(
    const f16_t* __restrict__ P, const f16_t* __restrict__ Vt,
    float* __restrict__ Out)
{
  __shared__ __align__(16) f16_t As[128 * 32];
  __shared__ __align__(16) f16_t Bs[128 * 32];
  const int m0 = blockIdx.x * 128;
  const int n0 = blockIdx.y * 128;
  const size_t poff  = (size_t)blockIdx.z * 2048 * 4096;
  const size_t vtoff = (size_t)blockIdx.z * 1024 * 2048;

  f32x4 acc[4][4] = {};
  gemm_core<4>(P + poff + (size_t)m0 * 4096, Vt + vtoff + (size_t)n0 * 2048,
               4096, 2048, 2048 / 32, As, Bs, acc);

  float* Ob = Out + (size_t)blockIdx.z * 2048 * 1024;
  const int lane = threadIdx.x & 63;
  const int w    = threadIdx.x >> 6;
  const int wr   = (w >> 1) * 64, wc = (w & 1) * 64;
  const int quad = lane >> 4,     l16 = lane & 15;

#pragma unroll
  for (int i = 0; i < 4; ++i)
#pragma unroll
    for (int j = 0; j < 4; ++j)
#pragma unroll
      for (int r = 0; r < 4; ++r) {
        const int row = m0 + wr + i * 16 + quad * 4 + r;
        const int col = n0 + wc + j * 16 + l16;
        Ob[(size_t)row * 1024 + col] = acc[i][j][r];
      }
}

// ---------------------------------------------------------------------------
extern "C" void kernel_launch(void* const* d_in, const int* in_sizes, int n_in,
                              void* d_out, int out_size, void* d_ws, size_t ws_size,
                              hipStream_t stream) {
  const float* x  = (const float*)d_in[0];
  const float* W1 = (const float*)d_in[1];
  const float* b1 = (const float*)d_in[2];
  const float* W2 = (const float*)d_in[3];
  const float* b2 = (const float*)d_in[4];
  float* out = (float*)d_out;

  const size_t QN = (size_t)8192 * 1024;
  const size_t WN = (size_t)1024 * 1024;
  f16_t* xh  = (f16_t*)d_ws;       // 16 MiB
  f16_t* W1h = xh + QN;            //  2 MiB
  f16_t* W2h = W1h + WN;           //  2 MiB
  f16_t* Q   = W2h + WN;           // 16 MiB
  f16_t* V   = Q + QN;             // 16 MiB
  f16_t* Vt  = V + QN;             // 16 MiB [4][1024][2048]
  float* S   = (float*)(Vt + QN);  // 64 MiB [4][2048][2048], P fp16 in-place

  dim3 blk(256);
  cvt_kernel<<<4096, blk, 0, stream>>>(x, xh);
  cvt_kernel<<<512, blk, 0, stream>>>(W1, W1h);
  cvt_kernel<<<512, blk, 0, stream>>>(W2, W2h);
  proj_qv_kernel<<<dim3(64, 8), blk, 0, stream>>>(xh, W1h, W2h, b1, b2, Q, V, Vt);
  score_kernel<<<dim3(8, 16, 4), blk, 0, stream>>>(Q, V, S);
  softmax_kernel<<<8192, blk, 0, stream>>>(S);
  out_kernel<<<dim3(16, 8, 4), blk, 0, stream>>>((const f16_t*)S, Vt, out);
}

// Round 4
// 269.361 us; speedup vs baseline: 1.1571x; 1.1571x over previous
//
#include <hip/hip_runtime.h>
#include <stdint.h>
#include <stddef.h>

// ---------------------------------------------------------------------------
// SelfAttention: out = softmax((x W1^T + b1)(x W2^T + b2)^T) (x W2^T + b2)
// B=4, L=2048, D=1024. fp32 in/out; fp16 MFMA internals.
// Round 4 vs round 3 (which regressed 277->312 on occupancy loss):
//  - score/out back to 128x128 tiles (4 blocks/CU), KEEP the XOR swizzle
//    (round 3 proved it: SQ_LDS_BANK_CONFLICT 4.19e6 -> 0)
//  - proj stays fused (x staged once) but 128x64 tiles -> grid 1024,
//    3-4 blocks/CU instead of 2; no transpose epilogue
//  - Vt produced by a dedicated conflict-free LDS transpose kernel
// ---------------------------------------------------------------------------

typedef _Float16  f16_t;
typedef _Float16  f16x8 __attribute__((ext_vector_type(8)));
typedef float     f32x4 __attribute__((ext_vector_type(4)));

__device__ __forceinline__ f32x4 mfma16(f16x8 a, f16x8 b, f32x4 c) {
  return __builtin_amdgcn_mfma_f32_16x16x32_f16(a, b, c, 0, 0, 0);
}

__device__ __forceinline__ void async_copy16(const f16_t* g, f16_t* l) {
  __builtin_amdgcn_global_load_lds(
      (const __attribute__((address_space(1))) unsigned int*)(g),
      (__attribute__((address_space(3))) unsigned int*)(l),
      16, 0, 0);
}

// C = A * B^T on a 128x128 tile, K = nk*32 contiguous in both.
// 4 waves 2x2, wave quadrant 64x64, acc[4][4]. LDS [row][32] with the 4
// 16B k-chunks of each row XOR-swizzled by (row>>1)&3 (conflict-free).
__device__ __forceinline__ void gemm_core(
    const f16_t* __restrict__ A, const f16_t* __restrict__ B,
    int lda, int ldb, int nk,
    f16_t* __restrict__ As, f16_t* __restrict__ Bs, f32x4 (&acc)[4][4])
{
  const int tid  = threadIdx.x;
  const int lane = tid & 63;
  const int w    = tid >> 6;
  const int wr   = (w >> 1) * 64;
  const int wc   = (w & 1) * 64;
  const int quad = lane >> 4;
  const int l16  = lane & 15;
  const int sw   = (quad ^ ((l16 >> 1) & 3)) * 8;

  const int r0  = tid >> 2;
  const int kc0 = ((tid & 3) ^ ((r0 >> 1) & 3)) * 8;

  const f16_t* Ag = A + (size_t)r0 * lda + kc0;
  const f16_t* Bg = B + (size_t)r0 * ldb + kc0;

  for (int kt = 0; kt < nk; ++kt) {
    async_copy16(Ag,                     As + tid * 8);
    async_copy16(Ag + (size_t)64 * lda,  As + (tid + 256) * 8);
    async_copy16(Bg,                     Bs + tid * 8);
    async_copy16(Bg + (size_t)64 * ldb,  Bs + (tid + 256) * 8);
    __syncthreads();

    f16x8 af[4], bf[4];
#pragma unroll
    for (int i = 0; i < 4; ++i) {
      af[i] = *(const f16x8*)(As + (wr + i * 16 + l16) * 32 + sw);
      bf[i] = *(const f16x8*)(Bs + (wc + i * 16 + l16) * 32 + sw);
    }
#pragma unroll
    for (int i = 0; i < 4; ++i)
#pragma unroll
      for (int j = 0; j < 4; ++j)
        acc[i][j] = mfma16(af[i], bf[j], acc[i][j]);

    __syncthreads();
    Ag += 32; Bg += 32;
  }
}

// ---------------------------------------------------------------------------
// 0) fp32 -> fp16 converter, 8 elems/thread.
__global__ __launch_bounds__(256) void cvt_kernel(
    const float* __restrict__ in, f16_t* __restrict__ out)
{
  const size_t i = ((size_t)blockIdx.x * 256 + threadIdx.x) * 8;
  f32x4 a = *(const f32x4*)(in + i);
  f32x4 b = *(const f32x4*)(in + i + 4);
  f16x8 o;
#pragma unroll
  for (int k = 0; k < 4; ++k) { o[k] = (f16_t)a[k]; o[k + 4] = (f16_t)b[k]; }
  *(f16x8*)(out + i) = o;
}

// ---------------------------------------------------------------------------
// 1) fused projection, 128x64 tiles: Q = xW1^T+b1, V = xW2^T+b2 (fp16).
//    x tile (128x32) staged once per iter for both GEMMs. Grid 64x16=1024.
__global__ __launch_bounds__(256) void proj_qv_kernel(
    const f16_t* __restrict__ X, const f16_t* __restrict__ W1,
    const f16_t* __restrict__ W2, const float* __restrict__ b1,
    const float* __restrict__ b2, f16_t* __restrict__ Q,
    f16_t* __restrict__ V)
{
  __shared__ __align__(16) f16_t Xs[128 * 32];   // 8 KB
  __shared__ __align__(16) f16_t W1s[64 * 32];   // 4 KB
  __shared__ __align__(16) f16_t W2s[64 * 32];   // 4 KB

  const int m0 = blockIdx.x * 128;
  const int n0 = blockIdx.y * 64;

  const int tid  = threadIdx.x;
  const int lane = tid & 63;
  const int w    = tid >> 6;
  const int wr   = (w >> 1) * 64;   // rows: 2 wave-rows of 64
  const int wc   = (w & 1) * 32;    // cols: 2 wave-cols of 32
  const int quad = lane >> 4;
  const int l16  = lane & 15;
  const int sw   = (quad ^ ((l16 >> 1) & 3)) * 8;
  const int r0   = tid >> 2;
  const int kc0  = ((tid & 3) ^ ((r0 >> 1) & 3)) * 8;

  const f16_t* Xg = X + (size_t)(m0 + r0) * 1024 + kc0;
  const f16_t* G1 = W1 + (size_t)(n0 + r0) * 1024 + kc0;   // r0<64 rows used
  const f16_t* G2 = W2 + (size_t)(n0 + r0) * 1024 + kc0;

  f32x4 accQ[4][2] = {};
  f32x4 accV[4][2] = {};

  for (int kt = 0; kt < 32; ++kt) {
    async_copy16(Xg,                     Xs + tid * 8);
    async_copy16(Xg + (size_t)64 * 1024, Xs + (tid + 256) * 8);
    async_copy16(G1,                     W1s + tid * 8);
    async_copy16(G2,                     W2s + tid * 8);
    __syncthreads();

    f16x8 xf[4], w1f[2], w2f[2];
#pragma unroll
    for (int i = 0; i < 4; ++i)
      xf[i] = *(const f16x8*)(Xs + (wr + i * 16 + l16) * 32 + sw);
#pragma unroll
    for (int j = 0; j < 2; ++j) {
      w1f[j] = *(const f16x8*)(W1s + (wc + j * 16 + l16) * 32 + sw);
      w2f[j] = *(const f16x8*)(W2s + (wc + j * 16 + l16) * 32 + sw);
    }
#pragma unroll
    for (int i = 0; i < 4; ++i)
#pragma unroll
      for (int j = 0; j < 2; ++j) {
        accQ[i][j] = mfma16(xf[i], w1f[j], accQ[i][j]);
        accV[i][j] = mfma16(xf[i], w2f[j], accV[i][j]);
      }
    __syncthreads();
    Xg += 32; G1 += 32; G2 += 32;
  }

#pragma unroll
  for (int j = 0; j < 2; ++j) {
    const int col = n0 + wc + j * 16 + l16;
    const float bq = b1[col], bv = b2[col];
#pragma unroll
    for (int i = 0; i < 4; ++i)
#pragma unroll
      for (int r = 0; r < 4; ++r) {
        const int row = m0 + wr + i * 16 + quad * 4 + r;
        Q[(size_t)row * 1024 + col] = (f16_t)(accQ[i][j][r] + bq);
        V[(size_t)row * 1024 + col] = (f16_t)(accV[i][j][r] + bv);
      }
  }
}

// ---------------------------------------------------------------------------
// 1b) Vt[b][d][key] = V[b][key][d]. 64x64 tiles through LDS; chunk placement
//     XOR-swizzled by (d>>3) -> conflict-free scalar writes, aligned b128
//     reads, coalesced global on both sides. Grid (32 key, 16 d, 4 b).
__global__ __launch_bounds__(256) void vt_kernel(
    const f16_t* __restrict__ V, f16_t* __restrict__ Vt)
{
  __shared__ __align__(16) f16_t Ls[64 * 64];   // 8 KB
  const int key0 = blockIdx.x * 64;
  const int d0   = blockIdx.y * 64;
  const size_t boff = (size_t)blockIdx.z * 2048 * 1024;

  const int tid = threadIdx.x;
#pragma unroll
  for (int rep = 0; rep < 2; ++rep) {
    const int kr = rep * 32 + (tid >> 3);   // key row 0..63
    const int dc = (tid & 7) * 8;           // d chunk base
    f16x8 v = *(const f16x8*)(V + boff + (size_t)(key0 + kr) * 1024 + d0 + dc);
#pragma unroll
    for (int e = 0; e < 8; ++e) {
      const int d = dc + e;
      // physical: d*64 + ((key>>3) ^ (d>>3))*8 + (key&7)
      Ls[d * 64 + (((kr >> 3) ^ (d >> 3)) << 3) + (kr & 7)] = v[e];
    }
  }
  __syncthreads();
#pragma unroll
  for (int rep = 0; rep < 2; ++rep) {
    const int d  = rep * 32 + (tid >> 3);   // out row (d) 0..63
    const int c  = tid & 7;                 // key chunk 0..7
    f16x8 v = *(const f16x8*)(Ls + d * 64 + ((c ^ (d >> 3)) << 3));
    *(f16x8*)(Vt + boff + (size_t)(d0 + d) * 2048 + key0 + c * 8) = v;
  }
}

// ---------------------------------------------------------------------------
// 2) scores: S[b][q][k] = Q[b,q,:] . V[b,k,:] (fp32). 128x128, grid 16x16x4.
__global__ __launch_bounds__(256) void score_kernel(
    const f16_t* __restrict__ Q, const f16_t* __restrict__ V,
    float* __restrict__ S)
{
  __shared__ __align__(16) f16_t As[128 * 32];
  __shared__ __align__(16) f16_t Bs[128 * 32];
  const int m0 = blockIdx.x * 128;
  const int n0 = blockIdx.y * 128;
  const size_t boff = (size_t)blockIdx.z * 2048 * 1024;

  f32x4 acc[4][4] = {};
  gemm_core(Q + boff + (size_t)m0 * 1024, V + boff + (size_t)n0 * 1024,
            1024, 1024, 1024 / 32, As, Bs, acc);

  float* Sb = S + (size_t)blockIdx.z * 2048 * 2048;
  const int lane = threadIdx.x & 63;
  const int w    = threadIdx.x >> 6;
  const int wr   = (w >> 1) * 64, wc = (w & 1) * 64;
  const int quad = lane >> 4,     l16 = lane & 15;

#pragma unroll
  for (int i = 0; i < 4; ++i)
#pragma unroll
    for (int j = 0; j < 4; ++j)
#pragma unroll
      for (int r = 0; r < 4; ++r) {
        const int row = m0 + wr + i * 16 + quad * 4 + r;
        const int col = n0 + wc + j * 16 + l16;
        Sb[(size_t)row * 2048 + col] = acc[i][j][r];
      }
}

// ---------------------------------------------------------------------------
// 3) softmax over each 2048-fp32 row of S; fp16 P written in-place.
__global__ __launch_bounds__(256) void softmax_kernel(float* __restrict__ S)
{
  float* src = S + (size_t)blockIdx.x * 2048;
  f16_t* dst = (f16_t*)src;
  const int tid  = threadIdx.x;
  const int lane = tid & 63;
  const int w    = tid >> 6;

  f32x4 va = *((const f32x4*)src + tid * 2);
  f32x4 vb = *((const f32x4*)src + tid * 2 + 1);
  float f[8];
#pragma unroll
  for (int k = 0; k < 4; ++k) { f[k] = va[k]; f[k + 4] = vb[k]; }

  float m = f[0];
#pragma unroll
  for (int k = 1; k < 8; ++k) m = fmaxf(m, f[k]);
#pragma unroll
  for (int off = 32; off >= 1; off >>= 1) m = fmaxf(m, __shfl_xor(m, off));

  __shared__ float red[4];
  if (lane == 0) red[w] = m;
  __syncthreads();
  m = fmaxf(fmaxf(red[0], red[1]), fmaxf(red[2], red[3]));

  float s = 0.f;
#pragma unroll
  for (int k = 0; k < 8; ++k) { f[k] = __expf(f[k] - m); s += f[k]; }
#pragma unroll
  for (int off = 32; off >= 1; off >>= 1) s += __shfl_xor(s, off);
  __syncthreads();
  if (lane == 0) red[w] = s;
  __syncthreads();
  s = (red[0] + red[1]) + (red[2] + red[3]);
  const float inv = 1.f / s;

  f16x8 o;
#pragma unroll
  for (int k = 0; k < 8; ++k) o[k] = (f16_t)(f[k] * inv);
  *((f16x8*)dst + tid) = o;
}

// ---------------------------------------------------------------------------
// 4) out[b][q][d] = sum_k P[b][q][k] * Vt[b][d][k] -> fp32. P pitch 4096 f16.
__global__ __launch_bounds__(256) void out_kernel(
    const f16_t* __restrict__ P, const f16_t* __restrict__ Vt,
    float* __restrict__ Out)
{
  __shared__ __align__(16) f16_t As[128 * 32];
  __shared__ __align__(16) f16_t Bs[128 * 32];
  const int m0 = blockIdx.x * 128;
  const int n0 = blockIdx.y * 128;
  const size_t poff  = (size_t)blockIdx.z * 2048 * 4096;
  const size_t vtoff = (size_t)blockIdx.z * 1024 * 2048;

  f32x4 acc[4][4] = {};
  gemm_core(P + poff + (size_t)m0 * 4096, Vt + vtoff + (size_t)n0 * 2048,
            4096, 2048, 2048 / 32, As, Bs, acc);

  float* Ob = Out + (size_t)blockIdx.z * 2048 * 1024;
  const int lane = threadIdx.x & 63;
  const int w    = threadIdx.x >> 6;
  const int wr   = (w >> 1) * 64, wc = (w & 1) * 64;
  const int quad = lane >> 4,     l16 = lane & 15;

#pragma unroll
  for (int i = 0; i < 4; ++i)
#pragma unroll
    for (int j = 0; j < 4; ++j)
#pragma unroll
      for (int r = 0; r < 4; ++r) {
        const int row = m0 + wr + i * 16 + quad * 4 + r;
        const int col = n0 + wc + j * 16 + l16;
        Ob[(size_t)row * 1024 + col] = acc[i][j][r];
      }
}

// ---------------------------------------------------------------------------
extern "C" void kernel_launch(void* const* d_in, const int* in_sizes, int n_in,
                              void* d_out, int out_size, void* d_ws, size_t ws_size,
                              hipStream_t stream) {
  const float* x  = (const float*)d_in[0];
  const float* W1 = (const float*)d_in[1];
  const float* b1 = (const float*)d_in[2];
  const float* W2 = (const float*)d_in[3];
  const float* b2 = (const float*)d_in[4];
  float* out = (float*)d_out;

  const size_t QN = (size_t)8192 * 1024;
  const size_t WN = (size_t)1024 * 1024;
  f16_t* xh  = (f16_t*)d_ws;       // 16 MiB
  f16_t* W1h = xh + QN;            //  2 MiB
  f16_t* W2h = W1h + WN;           //  2 MiB
  f16_t* Q   = W2h + WN;           // 16 MiB
  f16_t* V   = Q + QN;             // 16 MiB
  f16_t* Vt  = V + QN;             // 16 MiB [4][1024][2048]
  float* S   = (float*)(Vt + QN);  // 64 MiB [4][2048][2048], P fp16 in-place

  dim3 blk(256);
  cvt_kernel<<<4096, blk, 0, stream>>>(x, xh);
  cvt_kernel<<<512, blk, 0, stream>>>(W1, W1h);
  cvt_kernel<<<512, blk, 0, stream>>>(W2, W2h);
  proj_qv_kernel<<<dim3(64, 16), blk, 0, stream>>>(xh, W1h, W2h, b1, b2, Q, V);
  vt_kernel<<<dim3(32, 16, 4), blk, 0, stream>>>(V, Vt);
  score_kernel<<<dim3(16, 16, 4), blk, 0, stream>>>(Q, V, S);
  softmax_kernel<<<8192, blk, 0, stream>>>(S);
  out_kernel<<<dim3(16, 8, 4), blk, 0, stream>>>((const f16_t*)S, Vt, out);
}